// Round 1
// baseline (323.209 us; speedup 1.0000x reference)
//
#include <hip/hip_runtime.h>
#include <stdint.h>

#define BB 8
#define NN 4096
#define MM 32
#define KK 72
#define DD 78

static constexpr float LENC = 15.0f;
static constexpr float EPSF = 1e-12f;
static constexpr float BIGF = 100000.0f;

__device__ inline bool getmask(const void* masks, int flag, int i) {
  if (flag) return ((const unsigned char*)masks)[i] != 0;
  return ((const int*)masks)[i] != 0;
}

// ---------------- init: zero matchmask + maxima, detect mask dtype ----------
__global__ void k_init(unsigned* __restrict__ mmask, unsigned* __restrict__ maxima,
                       int* __restrict__ flag, const unsigned char* __restrict__ masks_raw) {
  int idx = blockIdx.x * blockDim.x + threadIdx.x;
  if (idx < BB * NN) mmask[idx] = 0u;
  if (idx < BB * 3) maxima[idx] = 0u;
  if (idx == 0) {
    // int32 masks: bytes at i%4!=0 (within first 256 bytes) are always 0.
    // bool/u8 masks: ~80% of them are 1. (256 bytes is valid either way.)
    int f = 0;
    for (int i = 1; i < BB * MM; ++i) {
      if ((i & 3) != 0 && masks_raw[i] != 0) { f = 1; break; }
    }
    *flag = f;
  }
}

// ---------------- pass A: per-pair dist/xy/th/iou + cls diffs + batch maxima -
__global__ __launch_bounds__(256) void k_pairs(
    const float* __restrict__ preds, const float* __restrict__ tgts,
    const int* __restrict__ imgw_p,
    float* __restrict__ dist, float* __restrict__ xyd, float* __restrict__ thd,
    float* __restrict__ iou, float* __restrict__ cls, unsigned* __restrict__ maxima) {
  __shared__ float t_xs[MM][KK];
  __shared__ float t_cx[MM], t_cy[MM], t_th[MM], t_len[MM];

  const int b = blockIdx.x >> 4;           // 16 blocks per batch (N/256)
  const int n0 = (blockIdx.x & 15) << 8;
  const int tid = threadIdx.x;
  const float imgw = (float)(*imgw_p);

  for (int idx = tid; idx < MM * DD; idx += 256) {
    int m = idx / DD, j = idx - m * DD;
    float v = tgts[((size_t)b * MM + m) * DD + j];
    if (j >= 6) t_xs[m][j - 6] = v;
    else if (j == 2) t_cx[m] = v;
    else if (j == 3) t_cy[m] = v;
    else if (j == 4) t_th[m] = v;
  }
  __syncthreads();
  if (tid < MM) {
    int V = 0;
    for (int k = 0; k < KK; ++k) {
      float t = t_xs[tid][k];
      if (t >= 0.0f && t < imgw) V++;
    }
    t_len[tid] = (float)(V > 0 ? V : 1);
  }
  __syncthreads();

  const int n = n0 + tid;
  const float* row = preds + ((size_t)b * NN + n) * DD;
  const float lg0 = row[0], lg1 = row[1];
  const float pcx = row[2], pcy = row[3], pth = row[4];
  float px[KK];
#pragma unroll
  for (int k = 0; k < KK; ++k) px[k] = row[6 + k];

  float md = 0.f, mxy = 0.f, mth = 0.f;
  for (int m = 0; m < MM; ++m) {
    float sad = 0.f, sov = 0.f, sun = 0.f;
#pragma unroll
    for (int k = 0; k < KK; ++k) {
      float t = t_xs[m][k];            // uniform across wave -> uniform branch
      if (t >= 0.0f && t < imgw) {
        float p = px[k];
        float ov = fminf(p + LENC, t + LENC) - fmaxf(p - LENC, t - LENC);
        float un = fmaxf(p + LENC, t + LENC) - fminf(p - LENC, t - LENC);
        sov += ov;
        sun += un;
        sad += fabsf(t - p);
      }
    }
    float dval = sad / t_len[m];
    float dx = pcx - t_cx[m], dy = pcy - t_cy[m];
    float xyv = sqrtf(dx * dx + dy * dy);
    float thv = fabsf(pth - t_th[m]);
    float iv = sov / (sun + 1e-9f);
    size_t o = ((size_t)(b * MM + m)) * NN + n;   // [b][m][n] layout
    dist[o] = dval;
    xyd[o] = xyv;
    thd[o] = thv;
    iou[o] = iv;
    md = fmaxf(md, dval);
    mxy = fmaxf(mxy, xyv);
    mth = fmaxf(mth, thv);
  }

  // focal-cost class diffs for both labels
#pragma unroll
  for (int c = 0; c < 2; ++c) {
    float lg = c ? lg1 : lg0;
    float p = 1.0f / (1.0f + expf(-lg));
    float neg = -logf(1.0f - p + EPSF) * 0.75f * (p * p);
    float pos = -logf(p + EPSF) * 0.25f * ((1.0f - p) * (1.0f - p));
    cls[((size_t)b * NN + n) * 2 + c] = pos - neg;
  }

  // wave reduce maxima, then atomics (values all >= 0 -> uint bit-compare ok)
  for (int off = 32; off; off >>= 1) {
    md = fmaxf(md, __shfl_down(md, off));
    mxy = fmaxf(mxy, __shfl_down(mxy, off));
    mth = fmaxf(mth, __shfl_down(mth, off));
  }
  if ((tid & 63) == 0) {
    atomicMax(&maxima[b * 3 + 0], __float_as_uint(md));
    atomicMax(&maxima[b * 3 + 1], __float_as_uint(mxy));
    atomicMax(&maxima[b * 3 + 2], __float_as_uint(mth));
  }
}

// ---------------- pass B: cost matrix ---------------------------------------
__global__ __launch_bounds__(256) void k_cost(
    const float* __restrict__ dist, const float* __restrict__ xyd,
    const float* __restrict__ thd, const float* __restrict__ cls,
    const float* __restrict__ tgts, const void* __restrict__ masks,
    const int* __restrict__ flag, const unsigned* __restrict__ maxima,
    float* __restrict__ cost) {
  int idx = blockIdx.x * 256 + threadIdx.x;   // over B*M*N
  if (idx >= BB * MM * NN) return;
  int b = idx / (MM * NN);
  int rem = idx - b * MM * NN;
  int m = rem / NN;
  int n = rem - m * NN;

  float maxd = fmaxf(__uint_as_float(maxima[b * 3 + 0]), 1e-6f);
  float maxxy = fmaxf(__uint_as_float(maxima[b * 3 + 1]), 1e-6f);
  float maxth = fmaxf(__uint_as_float(maxima[b * 3 + 2]), 1e-6f);

  float ds = (1.0f - dist[idx] / maxd) + 0.01f;
  float xs = (1.0f - xyd[idx] / maxxy) + 0.01f;
  float ts = (1.0f - thd[idx] / maxth) + 0.01f;

  int label = (int)tgts[((size_t)b * MM + m) * DD + 1];
  float cl = cls[((size_t)b * NN + n) * 2 + label];

  float r = (ds * xs) * ts;
  float c = -(r * r) * 3.0f + cl * 1.0f;
  bool mk = getmask(masks, *flag, b * MM + m);
  cost[idx] = mk ? c : BIGF;
}

// ---------------- pass C: per-(b,m) top-4 iou + top-4 lowest cost -----------
__global__ __launch_bounds__(64) void k_assign(
    const float* __restrict__ cost, const float* __restrict__ iou,
    const void* __restrict__ masks, const int* __restrict__ flag,
    unsigned* __restrict__ mmask) {
  const int b = blockIdx.x >> 5;
  const int m = blockIdx.x & 31;
  if (!getmask(masks, *flag, b * MM + m)) return;
  const int lane = threadIdx.x;
  const float* crow = cost + ((size_t)(b * MM + m)) * NN;
  const float* irow = iou + ((size_t)(b * MM + m)) * NN;

  float tc[4] = {3e38f, 3e38f, 3e38f, 3e38f};
  int ti[4] = {0x7fffffff, 0x7fffffff, 0x7fffffff, 0x7fffffff};
  float tv[4] = {-1.f, -1.f, -1.f, -1.f};

  for (int j = lane; j < NN; j += 64) {
    float c = crow[j];
    if (c < tc[3] || (c == tc[3] && j < ti[3])) {
      tc[3] = c; ti[3] = j;
#pragma unroll
      for (int s = 3; s > 0; --s) {
        bool sw = (tc[s] < tc[s - 1]) || (tc[s] == tc[s - 1] && ti[s] < ti[s - 1]);
        if (sw) {
          float fc = tc[s]; tc[s] = tc[s - 1]; tc[s - 1] = fc;
          int fi = ti[s]; ti[s] = ti[s - 1]; ti[s - 1] = fi;
        }
      }
    }
    float v = fmaxf(irow[j], 0.0f);
    if (v > tv[3]) {
      tv[3] = v;
#pragma unroll
      for (int s = 3; s > 0; --s) {
        if (tv[s] > tv[s - 1]) { float fv = tv[s]; tv[s] = tv[s - 1]; tv[s - 1] = fv; }
      }
    }
  }

  __shared__ float sc[64 * 4];
  __shared__ int si[64 * 4];
  __shared__ float sv[64 * 4];
#pragma unroll
  for (int s = 0; s < 4; ++s) {
    sc[lane * 4 + s] = tc[s];
    si[lane * 4 + s] = ti[s];
    sv[lane * 4 + s] = tv[s];
  }
  __syncthreads();

  if (lane == 0) {
    float gc[4] = {3e38f, 3e38f, 3e38f, 3e38f};
    int gi[4] = {0x7fffffff, 0x7fffffff, 0x7fffffff, 0x7fffffff};
    float gv[4] = {-1.f, -1.f, -1.f, -1.f};
    for (int e = 0; e < 64 * 4; ++e) {
      float c = sc[e]; int j = si[e];
      if (c < gc[3] || (c == gc[3] && j < gi[3])) {
        gc[3] = c; gi[3] = j;
#pragma unroll
        for (int s = 3; s > 0; --s) {
          bool sw = (gc[s] < gc[s - 1]) || (gc[s] == gc[s - 1] && gi[s] < gi[s - 1]);
          if (sw) {
            float fc = gc[s]; gc[s] = gc[s - 1]; gc[s - 1] = fc;
            int fi = gi[s]; gi[s] = gi[s - 1]; gi[s - 1] = fi;
          }
        }
      }
      float v = sv[e];
      if (v > gv[3]) {
        gv[3] = v;
#pragma unroll
        for (int s = 3; s > 0; --s) {
          if (gv[s] > gv[s - 1]) { float fv = gv[s]; gv[s] = gv[s - 1]; gv[s - 1] = fv; }
        }
      }
    }
    float ksum = ((gv[0] + gv[1]) + gv[2]) + gv[3];
    int k = (int)ksum;                 // trunc == floor (ksum >= 0)
    if (k < 1) k = 1;
    if (k > 4) k = 4;
    for (int s = 0; s < k; ++s) atomicOr(&mmask[(size_t)b * NN + gi[s]], 1u << m);
  }
}

// ---------------- pass D: conflict resolution + outputs ---------------------
__global__ __launch_bounds__(256) void k_final(
    const unsigned* __restrict__ mmask, const float* __restrict__ cost,
    int* __restrict__ out) {
  int idx = blockIdx.x * 256 + threadIdx.x;   // over B*N
  if (idx >= BB * NN) return;
  int b = idx >> 12;
  int n = idx & (NN - 1);
  unsigned mm = mmask[idx];
  int a, t;
  int pc = __popc(mm);
  if (pc == 0) {
    a = 0; t = -1;
  } else if (pc == 1) {
    a = 1; t = __ffs(mm) - 1;
  } else {
    a = 1;
    float best = 3e38f;
    int bi = -1;
    unsigned r = mm;
    while (r) {
      int m = __ffs(r) - 1;
      r &= r - 1;
      float c = cost[((size_t)(b * MM + m)) * NN + n];
      if (c < best) { best = c; bi = m; }   // strict < -> first (lowest m) wins ties
    }
    t = bi;
  }
  out[idx] = a;
  out[BB * NN + idx] = t;
}

extern "C" void kernel_launch(void* const* d_in, const int* in_sizes, int n_in,
                              void* d_out, int out_size, void* d_ws, size_t ws_size,
                              hipStream_t stream) {
  const float* preds = (const float*)d_in[0];
  const float* tgts = (const float*)d_in[1];
  const void* masks = d_in[2];
  const int* imgw = (const int*)d_in[3];

  char* ws = (char*)d_ws;
  const size_t MAT = (size_t)BB * MM * NN * sizeof(float);   // 4 MiB
  float* dist = (float*)(ws + 0 * MAT);
  float* xyd  = (float*)(ws + 1 * MAT);
  float* thd  = (float*)(ws + 2 * MAT);
  float* iou  = (float*)(ws + 3 * MAT);
  float* cost = (float*)(ws + 4 * MAT);
  float* cls  = (float*)(ws + 5 * MAT);                       // B*N*2 floats
  char* p = ws + 5 * MAT + (size_t)BB * NN * 2 * sizeof(float);
  unsigned* maxima = (unsigned*)p;                            // B*3
  unsigned* mmask = (unsigned*)(p + 256);                     // B*N
  int* flag = (int*)(p + 256 + (size_t)BB * NN * sizeof(unsigned));

  k_init<<<dim3((BB * NN + 255) / 256), dim3(256), 0, stream>>>(
      mmask, maxima, flag, (const unsigned char*)masks);
  k_pairs<<<dim3(BB * (NN / 256)), dim3(256), 0, stream>>>(
      preds, tgts, imgw, dist, xyd, thd, iou, cls, maxima);
  k_cost<<<dim3((BB * MM * NN + 255) / 256), dim3(256), 0, stream>>>(
      dist, xyd, thd, cls, tgts, masks, flag, maxima, cost);
  k_assign<<<dim3(BB * MM), dim3(64), 0, stream>>>(cost, iou, masks, flag, mmask);
  k_final<<<dim3((BB * NN + 255) / 256), dim3(256), 0, stream>>>(
      mmask, cost, (int*)d_out);
}

// Round 3
// 190.511 us; speedup vs baseline: 1.6965x; 1.6965x over previous
//
#include <hip/hip_runtime.h>
#include <stdint.h>

#define BB 8
#define NN 4096
#define MM 32
#define KK 72
#define DD 78
#define PAD 76            // LDS row stride (floats): 76*4=304 B, 16B-aligned, conflict-free

static constexpr float LENC = 15.0f;
static constexpr float EPSF = 1e-12f;
static constexpr float BIGF = 100000.0f;

__device__ inline bool getmask(const void* masks, int flag, int i) {
  if (flag) return ((const unsigned char*)masks)[i] != 0;
  return ((const int*)masks)[i] != 0;
}

// ---------- init: zero matchmask, detect mask dtype, focal-cost table -------
__global__ __launch_bounds__(256) void k_init(
    unsigned* __restrict__ mmask, int* __restrict__ flag,
    const unsigned char* __restrict__ masks_raw,
    const float* __restrict__ preds, float* __restrict__ cls) {
  int idx = blockIdx.x * 256 + threadIdx.x;     // over B*N
  if (idx >= BB * NN) return;
  mmask[idx] = 0u;
  if (idx == 0) {
    // int32 masks: bytes at i%4!=0 are always 0. bool/u8: ~80% are 1.
    int f = 0;
    for (int i = 1; i < BB * MM; ++i)
      if ((i & 3) != 0 && masks_raw[i] != 0) { f = 1; break; }
    *flag = f;
  }
  int b = idx >> 12, n = idx & (NN - 1);
  const float* row = preds + ((size_t)b * NN + n) * DD;
#pragma unroll
  for (int c = 0; c < 2; ++c) {
    float lg = row[c];
    float p = 1.0f / (1.0f + expf(-lg));
    float neg = -logf(1.0f - p + EPSF) * 0.75f * (p * p);
    float pos = -logf(p + EPSF) * 0.25f * ((1.0f - p) * (1.0f - p));
    cls[(size_t)idx * 2 + c] = pos - neg;
  }
}

// ---------- pass A: one thread per (n,m) pair --------------------------------
// grid: BB*512 blocks; block = 8 n  x 32 m  (256 threads)
__global__ __launch_bounds__(256) void k_pairs(
    const float* __restrict__ preds, const float* __restrict__ tgts,
    const int* __restrict__ imgw_p,
    float* __restrict__ dist, float* __restrict__ xyd, float* __restrict__ thd,
    float* __restrict__ iou, float* __restrict__ part) {
  __shared__ __align__(16) float t_xs[MM][PAD];
  __shared__ __align__(16) float px_s[8][PAD];
  __shared__ float t_cx[MM], t_cy[MM], t_th[MM], t_len[MM];
  __shared__ float redv[4][3];

  const int b = blockIdx.x >> 9;
  const int n0 = (blockIdx.x & 511) << 3;
  const int tid = threadIdx.x;
  const float imgw = (float)(*imgw_p);

  // stage targets for this batch
  for (int idx = tid; idx < MM * DD; idx += 256) {
    int m = idx / DD, j = idx - m * DD;
    float v = tgts[((size_t)b * MM + m) * DD + j];
    if (j >= 6) t_xs[m][j - 6] = v;
    else if (j == 2) t_cx[m] = v;
    else if (j == 3) t_cy[m] = v;
    else if (j == 4) t_th[m] = v;
  }
  // stage the 8 pred x-rows
  for (int idx = tid; idx < 8 * KK; idx += 256) {
    int ni = idx / KK, k = idx - ni * KK;
    px_s[ni][k] = preds[((size_t)b * NN + (n0 + ni)) * DD + 6 + k];
  }
  __syncthreads();
  if (tid < MM) {
    int V = 0;
    for (int k = 0; k < KK; ++k) {
      float t = t_xs[tid][k];
      if (t >= 0.0f && t < imgw) V++;
    }
    t_len[tid] = (float)(V > 0 ? V : 1);
  }
  __syncthreads();

  const int m = tid >> 3;        // 0..31
  const int ni = tid & 7;        // 0..7
  const int n = n0 + ni;

  float sad = 0.f, sov = 0.f, sun = 0.f;
  const float4* trow = reinterpret_cast<const float4*>(&t_xs[m][0]);
  const float4* prow = reinterpret_cast<const float4*>(&px_s[ni][0]);
#pragma unroll 6
  for (int q = 0; q < KK / 4; ++q) {
    float4 t4 = trow[q];
    float4 p4 = prow[q];
#pragma unroll
    for (int e = 0; e < 4; ++e) {
      float t = (e == 0) ? t4.x : (e == 1) ? t4.y : (e == 2) ? t4.z : t4.w;
      float p = (e == 0) ? p4.x : (e == 1) ? p4.y : (e == 2) ? p4.z : p4.w;
      bool valid = (t >= 0.0f) && (t < imgw);
      float lo = fminf(p, t), hi = fmaxf(p, t);
      float ov = (lo + LENC) - (hi - LENC);     // == min(p+L,t+L)-max(p-L,t-L)
      float un = (hi + LENC) - (lo - LENC);     // == max(p+L,t+L)-min(p-L,t-L)
      float d = hi - lo;                        // == |t-p| bitwise
      sov += valid ? ov : 0.0f;
      sun += valid ? un : 0.0f;
      sad += valid ? d : 0.0f;
    }
  }

  const float* prowg = preds + ((size_t)b * NN + n) * DD;
  const float pcx = prowg[2], pcy = prowg[3], pth = prowg[4];
  float dval = sad / t_len[m];
  float dx = pcx - t_cx[m], dy = pcy - t_cy[m];
  float xyv = sqrtf(dx * dx + dy * dy);
  float thv = fabsf(pth - t_th[m]);
  float iv = sov / (sun + 1e-9f);

  size_t o = ((size_t)(b * MM + m)) * NN + n;
  dist[o] = dval;
  xyd[o] = xyv;
  thd[o] = thv;
  iou[o] = iv;

  // block-level max of (dval, xyv, thv) -> plain store to part[block][3]
  float md = dval, mxy = xyv, mth = thv;
  for (int off = 32; off; off >>= 1) {
    md = fmaxf(md, __shfl_down(md, off));
    mxy = fmaxf(mxy, __shfl_down(mxy, off));
    mth = fmaxf(mth, __shfl_down(mth, off));
  }
  if ((tid & 63) == 0) {
    int w = tid >> 6;
    redv[w][0] = md; redv[w][1] = mxy; redv[w][2] = mth;
  }
  __syncthreads();
  if (tid == 0) {
    float a0 = fmaxf(fmaxf(redv[0][0], redv[1][0]), fmaxf(redv[2][0], redv[3][0]));
    float a1 = fmaxf(fmaxf(redv[0][1], redv[1][1]), fmaxf(redv[2][1], redv[3][1]));
    float a2 = fmaxf(fmaxf(redv[0][2], redv[1][2]), fmaxf(redv[2][2], redv[3][2]));
    part[(size_t)blockIdx.x * 3 + 0] = a0;
    part[(size_t)blockIdx.x * 3 + 1] = a1;
    part[(size_t)blockIdx.x * 3 + 2] = a2;
  }
}

// ---------- reduce per-block partial maxima -> maxima[b][3] -----------------
__global__ __launch_bounds__(64) void k_red(const float* __restrict__ part,
                                            float* __restrict__ maxima) {
  int b = blockIdx.x / 3, j = blockIdx.x - b * 3;
  int lane = threadIdx.x;
  float v = 0.f;
  for (int t = lane; t < 512; t += 64)
    v = fmaxf(v, part[((size_t)b * 512 + t) * 3 + j]);
  for (int off = 32; off; off >>= 1) v = fmaxf(v, __shfl_down(v, off));
  if (lane == 0) maxima[b * 3 + j] = v;
}

// ---------- pass B: cost matrix ---------------------------------------------
__global__ __launch_bounds__(256) void k_cost(
    const float* __restrict__ dist, const float* __restrict__ xyd,
    const float* __restrict__ thd, const float* __restrict__ cls,
    const float* __restrict__ tgts, const void* __restrict__ masks,
    const int* __restrict__ flag, const float* __restrict__ maxima,
    float* __restrict__ cost) {
  int idx = blockIdx.x * 256 + threadIdx.x;   // over B*M*N
  if (idx >= BB * MM * NN) return;
  int b = idx / (MM * NN);
  int rem = idx - b * MM * NN;
  int m = rem / NN;
  int n = rem - m * NN;

  float maxd = fmaxf(maxima[b * 3 + 0], 1e-6f);
  float maxxy = fmaxf(maxima[b * 3 + 1], 1e-6f);
  float maxth = fmaxf(maxima[b * 3 + 2], 1e-6f);

  float ds = (1.0f - dist[idx] / maxd) + 0.01f;
  float xs = (1.0f - xyd[idx] / maxxy) + 0.01f;
  float ts = (1.0f - thd[idx] / maxth) + 0.01f;

  int label = (int)tgts[((size_t)b * MM + m) * DD + 1];
  float cl = cls[((size_t)b * NN + n) * 2 + label];

  float r = (ds * xs) * ts;
  float c = -(r * r) * 3.0f + cl * 1.0f;
  bool mk = getmask(masks, *flag, b * MM + m);
  cost[idx] = mk ? c : BIGF;
}

// ---------- pass C: per-(b,m) top-4 iou + top-4 lowest cost -----------------
__global__ __launch_bounds__(64) void k_assign(
    const float* __restrict__ cost, const float* __restrict__ iou,
    const void* __restrict__ masks, const int* __restrict__ flag,
    unsigned* __restrict__ mmask) {
  const int b = blockIdx.x >> 5;
  const int m = blockIdx.x & 31;
  if (!getmask(masks, *flag, b * MM + m)) return;
  const int lane = threadIdx.x;
  const float* crow = cost + ((size_t)(b * MM + m)) * NN;
  const float* irow = iou + ((size_t)(b * MM + m)) * NN;

  float tc[4] = {3e38f, 3e38f, 3e38f, 3e38f};
  int ti[4] = {0x7fffffff, 0x7fffffff, 0x7fffffff, 0x7fffffff};
  float tv[4] = {-1.f, -1.f, -1.f, -1.f};

  for (int j = lane; j < NN; j += 64) {
    float c = crow[j];
    if (c < tc[3] || (c == tc[3] && j < ti[3])) {
      tc[3] = c; ti[3] = j;
#pragma unroll
      for (int s = 3; s > 0; --s) {
        bool sw = (tc[s] < tc[s - 1]) || (tc[s] == tc[s - 1] && ti[s] < ti[s - 1]);
        if (sw) {
          float fc = tc[s]; tc[s] = tc[s - 1]; tc[s - 1] = fc;
          int fi = ti[s]; ti[s] = ti[s - 1]; ti[s - 1] = fi;
        }
      }
    }
    float v = fmaxf(irow[j], 0.0f);
    if (v > tv[3]) {
      tv[3] = v;
#pragma unroll
      for (int s = 3; s > 0; --s) {
        if (tv[s] > tv[s - 1]) { float fv = tv[s]; tv[s] = tv[s - 1]; tv[s - 1] = fv; }
      }
    }
  }

  __shared__ float sc[64 * 4];
  __shared__ int si[64 * 4];
  __shared__ float sv[64 * 4];
#pragma unroll
  for (int s = 0; s < 4; ++s) {
    sc[lane * 4 + s] = tc[s];
    si[lane * 4 + s] = ti[s];
    sv[lane * 4 + s] = tv[s];
  }
  __syncthreads();

  if (lane == 0) {
    float gc[4] = {3e38f, 3e38f, 3e38f, 3e38f};
    int gi[4] = {0x7fffffff, 0x7fffffff, 0x7fffffff, 0x7fffffff};
    float gv[4] = {-1.f, -1.f, -1.f, -1.f};
    for (int e = 0; e < 64 * 4; ++e) {
      float c = sc[e]; int j = si[e];
      if (c < gc[3] || (c == gc[3] && j < gi[3])) {
        gc[3] = c; gi[3] = j;
#pragma unroll
        for (int s = 3; s > 0; --s) {
          bool sw = (gc[s] < gc[s - 1]) || (gc[s] == gc[s - 1] && gi[s] < gi[s - 1]);
          if (sw) {
            float fc = gc[s]; gc[s] = gc[s - 1]; gc[s - 1] = fc;
            int fi = gi[s]; gi[s] = gi[s - 1]; gi[s - 1] = fi;
          }
        }
      }
      float v = sv[e];
      if (v > gv[3]) {
        gv[3] = v;
#pragma unroll
        for (int s = 3; s > 0; --s) {
          if (gv[s] > gv[s - 1]) { float fv = gv[s]; gv[s] = gv[s - 1]; gv[s - 1] = fv; }
        }
      }
    }
    float ksum = ((gv[0] + gv[1]) + gv[2]) + gv[3];
    int k = (int)ksum;
    if (k < 1) k = 1;
    if (k > 4) k = 4;
    for (int s = 0; s < k; ++s) atomicOr(&mmask[(size_t)b * NN + gi[s]], 1u << m);
  }
}

// ---------- pass D: conflict resolution + outputs ---------------------------
__global__ __launch_bounds__(256) void k_final(
    const unsigned* __restrict__ mmask, const float* __restrict__ cost,
    int* __restrict__ out) {
  int idx = blockIdx.x * 256 + threadIdx.x;   // over B*N
  if (idx >= BB * NN) return;
  int b = idx >> 12;
  int n = idx & (NN - 1);
  unsigned mm = mmask[idx];
  int a, t;
  int pc = __popc(mm);
  if (pc == 0) {
    a = 0; t = -1;
  } else if (pc == 1) {
    a = 1; t = __ffs(mm) - 1;
  } else {
    a = 1;
    float best = 3e38f;
    int bi = -1;
    unsigned r = mm;
    while (r) {
      int m = __ffs(r) - 1;
      r &= r - 1;
      float c = cost[((size_t)(b * MM + m)) * NN + n];
      if (c < best) { best = c; bi = m; }
    }
    t = bi;
  }
  out[idx] = a;
  out[BB * NN + idx] = t;
}

extern "C" void kernel_launch(void* const* d_in, const int* in_sizes, int n_in,
                              void* d_out, int out_size, void* d_ws, size_t ws_size,
                              hipStream_t stream) {
  const float* preds = (const float*)d_in[0];
  const float* tgts = (const float*)d_in[1];
  const void* masks = d_in[2];
  const int* imgw = (const int*)d_in[3];

  char* ws = (char*)d_ws;
  const size_t MAT = (size_t)BB * MM * NN * sizeof(float);   // 4 MiB
  float* dist = (float*)(ws + 0 * MAT);
  float* xyd  = (float*)(ws + 1 * MAT);
  float* thd  = (float*)(ws + 2 * MAT);
  float* iou  = (float*)(ws + 3 * MAT);
  float* cost = (float*)(ws + 4 * MAT);
  float* cls  = (float*)(ws + 5 * MAT);                       // B*N*2 floats
  char* p = ws + 5 * MAT + (size_t)BB * NN * 2 * sizeof(float);
  float* part = (float*)p;                                    // 4096*3 floats
  p += (size_t)BB * 512 * 3 * sizeof(float);
  float* maxima = (float*)p;                                  // B*3
  p += 256;
  unsigned* mmask = (unsigned*)p;                             // B*N
  p += (size_t)BB * NN * sizeof(unsigned);
  int* flag = (int*)p;

  k_init<<<dim3((BB * NN + 255) / 256), dim3(256), 0, stream>>>(
      mmask, flag, (const unsigned char*)masks, preds, cls);
  k_pairs<<<dim3(BB * 512), dim3(256), 0, stream>>>(
      preds, tgts, imgw, dist, xyd, thd, iou, part);
  k_red<<<dim3(BB * 3), dim3(64), 0, stream>>>(part, maxima);
  k_cost<<<dim3((BB * MM * NN + 255) / 256), dim3(256), 0, stream>>>(
      dist, xyd, thd, cls, tgts, masks, flag, maxima, cost);
  k_assign<<<dim3(BB * MM), dim3(64), 0, stream>>>(cost, iou, masks, flag, mmask);
  k_final<<<dim3((BB * NN + 255) / 256), dim3(256), 0, stream>>>(
      mmask, cost, (int*)d_out);
}

// Round 4
// 101.730 us; speedup vs baseline: 3.1771x; 1.8727x over previous
//
#include <hip/hip_runtime.h>
#include <stdint.h>

#define BB 8
#define NN 4096
#define MM 32
#define KK 72
#define DD 78
#define PAD 76            // LDS row stride (floats): 76*4=304 B, 16B-aligned, conflict-free

static constexpr float LENC = 15.0f;
static constexpr float EPSF = 1e-12f;

__device__ inline bool getmask(const void* masks, int flag, int i) {
  if (flag) return ((const unsigned char*)masks)[i] != 0;
  return ((const int*)masks)[i] != 0;
}

// ---------- init: zero matchmask, detect mask dtype, focal-cost table -------
__global__ __launch_bounds__(256) void k_init(
    unsigned* __restrict__ mmask, int* __restrict__ flag,
    const unsigned char* __restrict__ masks_raw,
    const float* __restrict__ preds, float* __restrict__ cls) {
  int idx = blockIdx.x * 256 + threadIdx.x;     // over B*N
  if (idx >= BB * NN) return;
  mmask[idx] = 0u;
  if (idx == 0) {
    // int32 masks: bytes at i%4!=0 are always 0. bool/u8: ~80% are 1.
    int f = 0;
    for (int i = 1; i < BB * MM; ++i)
      if ((i & 3) != 0 && masks_raw[i] != 0) { f = 1; break; }
    *flag = f;
  }
  int b = idx >> 12, n = idx & (NN - 1);
  const float* row = preds + ((size_t)b * NN + n) * DD;
#pragma unroll
  for (int c = 0; c < 2; ++c) {
    float lg = row[c];
    float p = 1.0f / (1.0f + expf(-lg));
    float neg = -logf(1.0f - p + EPSF) * 0.75f * (p * p);
    float pos = -logf(p + EPSF) * 0.25f * ((1.0f - p) * (1.0f - p));
    cls[(size_t)idx * 2 + c] = pos - neg;
  }
}

// ---------- pass A: one thread per (n,m) pair --------------------------------
// grid: BB*512 blocks; block = 8 n  x 32 m  (256 threads)
__global__ __launch_bounds__(256) void k_pairs(
    const float* __restrict__ preds, const float* __restrict__ tgts,
    const int* __restrict__ imgw_p,
    float* __restrict__ dist, float* __restrict__ xyd, float* __restrict__ thd,
    float* __restrict__ iou, float* __restrict__ part) {
  __shared__ __align__(16) float t_xs[MM][PAD];
  __shared__ __align__(16) float px_s[8][PAD];
  __shared__ float t_cx[MM], t_cy[MM], t_th[MM], t_len[MM];
  __shared__ float redv[4][3];

  const int b = blockIdx.x >> 9;
  const int n0 = (blockIdx.x & 511) << 3;
  const int tid = threadIdx.x;
  const float imgw = (float)(*imgw_p);

  // stage targets for this batch
  for (int idx = tid; idx < MM * DD; idx += 256) {
    int m = idx / DD, j = idx - m * DD;
    float v = tgts[((size_t)b * MM + m) * DD + j];
    if (j >= 6) t_xs[m][j - 6] = v;
    else if (j == 2) t_cx[m] = v;
    else if (j == 3) t_cy[m] = v;
    else if (j == 4) t_th[m] = v;
  }
  // stage the 8 pred x-rows
  for (int idx = tid; idx < 8 * KK; idx += 256) {
    int ni = idx / KK, k = idx - ni * KK;
    px_s[ni][k] = preds[((size_t)b * NN + (n0 + ni)) * DD + 6 + k];
  }
  __syncthreads();
  if (tid < MM) {
    int V = 0;
    for (int k = 0; k < KK; ++k) {
      float t = t_xs[tid][k];
      if (t >= 0.0f && t < imgw) V++;
    }
    t_len[tid] = (float)(V > 0 ? V : 1);
  }
  __syncthreads();

  const int m = tid >> 3;        // 0..31
  const int ni = tid & 7;        // 0..7
  const int n = n0 + ni;

  float sad = 0.f, sov = 0.f, sun = 0.f;
  const float4* trow = reinterpret_cast<const float4*>(&t_xs[m][0]);
  const float4* prow = reinterpret_cast<const float4*>(&px_s[ni][0]);
#pragma unroll 6
  for (int q = 0; q < KK / 4; ++q) {
    float4 t4 = trow[q];
    float4 p4 = prow[q];
#pragma unroll
    for (int e = 0; e < 4; ++e) {
      float t = (e == 0) ? t4.x : (e == 1) ? t4.y : (e == 2) ? t4.z : t4.w;
      float p = (e == 0) ? p4.x : (e == 1) ? p4.y : (e == 2) ? p4.z : p4.w;
      bool valid = (t >= 0.0f) && (t < imgw);
      float lo = fminf(p, t), hi = fmaxf(p, t);
      float ov = (lo + LENC) - (hi - LENC);     // == min(p+L,t+L)-max(p-L,t-L)
      float un = (hi + LENC) - (lo - LENC);     // == max(p+L,t+L)-min(p-L,t-L)
      float d = hi - lo;                        // == |t-p| bitwise
      sov += valid ? ov : 0.0f;
      sun += valid ? un : 0.0f;
      sad += valid ? d : 0.0f;
    }
  }

  const float* prowg = preds + ((size_t)b * NN + n) * DD;
  const float pcx = prowg[2], pcy = prowg[3], pth = prowg[4];
  float dval = sad / t_len[m];
  float dx = pcx - t_cx[m], dy = pcy - t_cy[m];
  float xyv = sqrtf(dx * dx + dy * dy);
  float thv = fabsf(pth - t_th[m]);
  float iv = sov / (sun + 1e-9f);

  size_t o = ((size_t)(b * MM + m)) * NN + n;
  dist[o] = dval;
  xyd[o] = xyv;
  thd[o] = thv;
  iou[o] = iv;

  // block-level max of (dval, xyv, thv) -> plain store to part[block][3]
  float md = dval, mxy = xyv, mth = thv;
  for (int off = 32; off; off >>= 1) {
    md = fmaxf(md, __shfl_down(md, off));
    mxy = fmaxf(mxy, __shfl_down(mxy, off));
    mth = fmaxf(mth, __shfl_down(mth, off));
  }
  if ((tid & 63) == 0) {
    int w = tid >> 6;
    redv[w][0] = md; redv[w][1] = mxy; redv[w][2] = mth;
  }
  __syncthreads();
  if (tid == 0) {
    float a0 = fmaxf(fmaxf(redv[0][0], redv[1][0]), fmaxf(redv[2][0], redv[3][0]));
    float a1 = fmaxf(fmaxf(redv[0][1], redv[1][1]), fmaxf(redv[2][1], redv[3][1]));
    float a2 = fmaxf(fmaxf(redv[0][2], redv[1][2]), fmaxf(redv[2][2], redv[3][2]));
    part[(size_t)blockIdx.x * 3 + 0] = a0;
    part[(size_t)blockIdx.x * 3 + 1] = a1;
    part[(size_t)blockIdx.x * 3 + 2] = a2;
  }
}

// ---------- reduce per-block partial maxima -> maxima[b][3] -----------------
__global__ __launch_bounds__(64) void k_red(const float* __restrict__ part,
                                            float* __restrict__ maxima) {
  int b = blockIdx.x / 3, j = blockIdx.x - b * 3;
  int lane = threadIdx.x;
  float v = 0.f;
  for (int t = lane; t < 512; t += 64)
    v = fmaxf(v, part[((size_t)b * 512 + t) * 3 + j]);
  for (int off = 32; off; off >>= 1) v = fmaxf(v, __shfl_down(v, off));
  if (lane == 0) maxima[b * 3 + j] = v;
}

// ---------- pass C: fused cost + per-(b,m) top-4 selection ------------------
// one block (1024 threads = 16 waves) per (b,m); thread t owns n = 4t..4t+3
__global__ __launch_bounds__(1024) void k_assign(
    const float* __restrict__ dist, const float* __restrict__ xyd,
    const float* __restrict__ thd, const float* __restrict__ iou,
    const float* __restrict__ cls, const float* __restrict__ tgts,
    const float* __restrict__ maxima, const void* __restrict__ masks,
    const int* __restrict__ flag, unsigned* __restrict__ mmask) {
  const int b = blockIdx.x >> 5;
  const int m = blockIdx.x & 31;
  if (!getmask(masks, *flag, b * MM + m)) return;   // block-uniform exit

  const int tid = threadIdx.x;
  const int n0 = tid << 2;
  const size_t o = ((size_t)(b * MM + m)) * NN + n0;

  const float maxd = fmaxf(maxima[b * 3 + 0], 1e-6f);
  const float maxxy = fmaxf(maxima[b * 3 + 1], 1e-6f);
  const float maxth = fmaxf(maxima[b * 3 + 2], 1e-6f);
  const int label = (int)tgts[((size_t)b * MM + m) * DD + 1];

  float4 d4 = *reinterpret_cast<const float4*>(dist + o);
  float4 x4 = *reinterpret_cast<const float4*>(xyd + o);
  float4 t4 = *reinterpret_cast<const float4*>(thd + o);
  float4 i4 = *reinterpret_cast<const float4*>(iou + o);
  const float4* cbase = reinterpret_cast<const float4*>(cls + ((size_t)b * NN + n0) * 2);
  float4 c0 = cbase[0], c1 = cbase[1];

  float de[4] = {d4.x, d4.y, d4.z, d4.w};
  float xe[4] = {x4.x, x4.y, x4.z, x4.w};
  float te[4] = {t4.x, t4.y, t4.z, t4.w};
  float ie[4] = {i4.x, i4.y, i4.z, i4.w};
  float clv[4] = {label ? c0.y : c0.x, label ? c0.w : c0.z,
                  label ? c1.y : c1.x, label ? c1.w : c1.z};

  float cc[4]; int ci[4]; float vv[4];
#pragma unroll
  for (int e = 0; e < 4; ++e) {
    float ds = (1.0f - de[e] / maxd) + 0.01f;
    float xs = (1.0f - xe[e] / maxxy) + 0.01f;
    float ts = (1.0f - te[e] / maxth) + 0.01f;
    float r = (ds * xs) * ts;
    cc[e] = -(r * r) * 3.0f + clv[e] * 1.0f;
    ci[e] = n0 + e;
    vv[e] = fmaxf(ie[e], 0.0f);
  }

  __shared__ float ls_c[64];  __shared__ int ls_ci[64];
  __shared__ float ls_v[64];  __shared__ int ls_vi[64];

  const int wid = tid >> 6, lane = tid & 63;
  unsigned usedC = 0, usedV = 0;
  float wcv[4]; int wci[4]; float wvv[4]; int wvi[4];

#pragma unroll
  for (int r = 0; r < 4; ++r) {
    // ---- cost: extract global (wave) min by (c, idx) ----
    float bv = 3e38f; int bi = 0x7fffffff; int be = -1;
#pragma unroll
    for (int e = 0; e < 4; ++e)
      if (!((usedC >> e) & 1) && (cc[e] < bv || (cc[e] == bv && ci[e] < bi))) {
        bv = cc[e]; bi = ci[e]; be = e;
      }
    float v = bv; int i = bi;
#pragma unroll
    for (int off = 32; off; off >>= 1) {
      float ov = __shfl_xor(v, off); int oi = __shfl_xor(i, off);
      if (ov < v || (ov == v && oi < i)) { v = ov; i = oi; }
    }
    if (be >= 0 && i == bi) usedC |= 1u << be;   // unique n -> unique winner
    wcv[r] = v; wci[r] = i;

    // ---- iou: extract global (wave) max by (v desc, idx asc) ----
    float bw = -1.0f; int bj = 0x7fffffff; int bf = -1;
#pragma unroll
    for (int e = 0; e < 4; ++e)
      if (!((usedV >> e) & 1) && (vv[e] > bw || (vv[e] == bw && ci[e] < bj))) {
        bw = vv[e]; bj = ci[e]; bf = e;
      }
    float w = bw; int j = bj;
#pragma unroll
    for (int off = 32; off; off >>= 1) {
      float ow = __shfl_xor(w, off); int oj = __shfl_xor(j, off);
      if (ow > w || (ow == w && oj < j)) { w = ow; j = oj; }
    }
    if (bf >= 0 && j == bj) usedV |= 1u << bf;
    wvv[r] = w; wvi[r] = j;
  }

  if (lane == 0) {
#pragma unroll
    for (int r = 0; r < 4; ++r) {
      ls_c[wid * 4 + r] = wcv[r]; ls_ci[wid * 4 + r] = wci[r];
      ls_v[wid * 4 + r] = wvv[r]; ls_vi[wid * 4 + r] = wvi[r];
    }
  }
  __syncthreads();

  if (tid < 64) {
    float c = ls_c[tid]; int i = ls_ci[tid];
    float w = ls_v[tid]; int j = ls_vi[tid];
    int gidx[4]; float gsum = 0.0f;
#pragma unroll
    for (int r = 0; r < 4; ++r) {
      float v = c; int vi = i;
#pragma unroll
      for (int off = 32; off; off >>= 1) {
        float ov = __shfl_xor(v, off); int oi = __shfl_xor(vi, off);
        if (ov < v || (ov == v && oi < vi)) { v = ov; vi = oi; }
      }
      if (i == vi) c = 3e38f;                    // consume winner
      gidx[r] = vi;

      float u = w; int ui = j;
#pragma unroll
      for (int off = 32; off; off >>= 1) {
        float ou = __shfl_xor(u, off); int oi = __shfl_xor(ui, off);
        if (ou > u || (ou == u && oi < ui)) { u = ou; ui = oi; }
      }
      if (j == ui) w = -1.0f;
      gsum += u;
    }
    if (tid == 0) {
      int k = (int)gsum;                         // trunc == floor (gsum >= 0)
      if (k < 1) k = 1;
      if (k > 4) k = 4;
      for (int s = 0; s < k; ++s)
        atomicOr(&mmask[(size_t)b * NN + gidx[s]], 1u << m);
    }
  }
}

// ---------- pass D: conflict resolution + outputs ---------------------------
__global__ __launch_bounds__(256) void k_final(
    const unsigned* __restrict__ mmask, const float* __restrict__ dist,
    const float* __restrict__ xyd, const float* __restrict__ thd,
    const float* __restrict__ cls, const float* __restrict__ tgts,
    const float* __restrict__ maxima, int* __restrict__ out) {
  int idx = blockIdx.x * 256 + threadIdx.x;   // over B*N
  if (idx >= BB * NN) return;
  int b = idx >> 12;
  int n = idx & (NN - 1);
  unsigned mm = mmask[idx];
  int a, t;
  int pc = __popc(mm);
  if (pc == 0) {
    a = 0; t = -1;
  } else if (pc == 1) {
    a = 1; t = __ffs(mm) - 1;
  } else {
    a = 1;
    float maxd = fmaxf(maxima[b * 3 + 0], 1e-6f);
    float maxxy = fmaxf(maxima[b * 3 + 1], 1e-6f);
    float maxth = fmaxf(maxima[b * 3 + 2], 1e-6f);
    float best = 3e38f;
    int bi = -1;
    unsigned r0 = mm;
    while (r0) {
      int m = __ffs(r0) - 1;
      r0 &= r0 - 1;
      size_t o = ((size_t)(b * MM + m)) * NN + n;
      int label = (int)tgts[((size_t)b * MM + m) * DD + 1];
      float ds = (1.0f - dist[o] / maxd) + 0.01f;
      float xs = (1.0f - xyd[o] / maxxy) + 0.01f;
      float ts = (1.0f - thd[o] / maxth) + 0.01f;
      float r = (ds * xs) * ts;
      float c = -(r * r) * 3.0f + cls[((size_t)b * NN + n) * 2 + label] * 1.0f;
      if (c < best) { best = c; bi = m; }   // strict < -> lowest m wins ties
    }
    t = bi;
  }
  out[idx] = a;
  out[BB * NN + idx] = t;
}

extern "C" void kernel_launch(void* const* d_in, const int* in_sizes, int n_in,
                              void* d_out, int out_size, void* d_ws, size_t ws_size,
                              hipStream_t stream) {
  const float* preds = (const float*)d_in[0];
  const float* tgts = (const float*)d_in[1];
  const void* masks = d_in[2];
  const int* imgw = (const int*)d_in[3];

  char* ws = (char*)d_ws;
  const size_t MAT = (size_t)BB * MM * NN * sizeof(float);   // 4 MiB
  float* dist = (float*)(ws + 0 * MAT);
  float* xyd  = (float*)(ws + 1 * MAT);
  float* thd  = (float*)(ws + 2 * MAT);
  float* iou  = (float*)(ws + 3 * MAT);
  float* cls  = (float*)(ws + 4 * MAT);                       // B*N*2 floats
  char* p = ws + 4 * MAT + (size_t)BB * NN * 2 * sizeof(float);
  float* part = (float*)p;                                    // B*512*3 floats
  p += (size_t)BB * 512 * 3 * sizeof(float);
  float* maxima = (float*)p;                                  // B*3
  p += 256;
  unsigned* mmask = (unsigned*)p;                             // B*N
  p += (size_t)BB * NN * sizeof(unsigned);
  int* flag = (int*)p;

  k_init<<<dim3((BB * NN + 255) / 256), dim3(256), 0, stream>>>(
      mmask, flag, (const unsigned char*)masks, preds, cls);
  k_pairs<<<dim3(BB * 512), dim3(256), 0, stream>>>(
      preds, tgts, imgw, dist, xyd, thd, iou, part);
  k_red<<<dim3(BB * 3), dim3(64), 0, stream>>>(part, maxima);
  k_assign<<<dim3(BB * MM), dim3(1024), 0, stream>>>(
      dist, xyd, thd, iou, cls, tgts, maxima, masks, flag, mmask);
  k_final<<<dim3((BB * NN + 255) / 256), dim3(256), 0, stream>>>(
      mmask, dist, xyd, thd, cls, tgts, maxima, (int*)d_out);
}